// Round 1
// baseline (311.143 us; speedup 1.0000x reference)
//
#include <hip/hip_runtime.h>
#include <math.h>

#define D 512
#define TEMP_INV 14.285714285714286f  // 1/0.07

// ws layout (floats):
//   [0]            neg_sum accumulator
//   [64 .. 64+2048) p values (positive-pair logits S[2k,2k+1])
//   [4096 .. 8192) rnorm[4096]
// total 32 KB

__global__ void infonce_rnorm_kernel(const float* __restrict__ emb,
                                     float* __restrict__ ws, int nrows) {
    if (blockIdx.x == 0 && threadIdx.x == 0) ws[0] = 0.0f;  // zero neg_sum
    const int lane = threadIdx.x & 63;
    const int wave = threadIdx.x >> 6;
    const int row = blockIdx.x * 4 + wave;
    if (row >= nrows) return;
    const float* r = emb + (size_t)row * D;
    float4 v1 = *(const float4*)&r[lane * 4];
    float4 v2 = *(const float4*)&r[256 + lane * 4];
    float s = v1.x * v1.x + v1.y * v1.y + v1.z * v1.z + v1.w * v1.w
            + v2.x * v2.x + v2.y * v2.y + v2.z * v2.z + v2.w * v2.w;
    #pragma unroll
    for (int off = 32; off > 0; off >>= 1) s += __shfl_down(s, off, 64);
    if (lane == 0) ws[4096 + row] = rsqrtf(s);
}

// 64x64 tile per block, 256 threads, 4x4 accumulators/thread, BK=32.
__global__ __launch_bounds__(256) void infonce_sim_kernel(
        const float* __restrict__ emb, const int* __restrict__ labels,
        float* __restrict__ ws) {
    const int bi = blockIdx.y;  // row-block
    const int bj = blockIdx.x;  // col-block
    if (bj < bi) return;        // strict-lower blocks contribute nothing

    __shared__ float As[32][65];  // [k][m], +1 pad breaks store conflicts
    __shared__ float Bs[32][65];  // [k][n]
    __shared__ float red[4];

    const float* __restrict__ rnorm = ws + 4096;
    float* __restrict__ pvals = ws + 64;

    const int t = threadIdx.x;
    const int tx = t & 15;    // 0..15 -> col group
    const int ty = t >> 4;    // 0..15 -> row group
    const int rowA0 = bi * 64;
    const int rowB0 = bj * 64;

    float acc[4][4] = {};

    for (int k0 = 0; k0 < D; k0 += 32) {
        // Stage A and B tiles (64 rows x 32 k), normalization fused on load.
        #pragma unroll
        for (int l = 0; l < 2; ++l) {
            const int idx4 = l * 256 + t;       // 0..511 float4 slots
            const int row = idx4 >> 3;          // 8 float4 per row
            const int kc = (idx4 & 7) << 2;     // 0,4,...,28
            float4 va = *(const float4*)&emb[(size_t)(rowA0 + row) * D + k0 + kc];
            const float rna = rnorm[rowA0 + row];
            As[kc + 0][row] = va.x * rna;
            As[kc + 1][row] = va.y * rna;
            As[kc + 2][row] = va.z * rna;
            As[kc + 3][row] = va.w * rna;
            float4 vb = *(const float4*)&emb[(size_t)(rowB0 + row) * D + k0 + kc];
            const float rnb = rnorm[rowB0 + row];
            Bs[kc + 0][row] = vb.x * rnb;
            Bs[kc + 1][row] = vb.y * rnb;
            Bs[kc + 2][row] = vb.z * rnb;
            Bs[kc + 3][row] = vb.w * rnb;
        }
        __syncthreads();
        #pragma unroll
        for (int k = 0; k < 32; ++k) {
            float af[4], bf[4];
            #pragma unroll
            for (int a = 0; a < 4; ++a) af[a] = As[k][ty * 4 + a];
            #pragma unroll
            for (int b = 0; b < 4; ++b) bf[b] = Bs[k][tx * 4 + b];
            #pragma unroll
            for (int a = 0; a < 4; ++a)
                #pragma unroll
                for (int b = 0; b < 4; ++b)
                    acc[a][b] = fmaf(af[a], bf[b], acc[a][b]);
        }
        __syncthreads();
    }

    // Epilogue: mask, exp, reduce.
    int labr[4], labc[4];
    #pragma unroll
    for (int a = 0; a < 4; ++a) labr[a] = labels[(rowA0 + ty * 4 + a) >> 1];
    #pragma unroll
    for (int b = 0; b < 4; ++b) labc[b] = labels[(rowB0 + tx * 4 + b) >> 1];

    float neg_local = 0.0f;
    #pragma unroll
    for (int a = 0; a < 4; ++a) {
        const int i = rowA0 + ty * 4 + a;
        #pragma unroll
        for (int b = 0; b < 4; ++b) {
            const int j = rowB0 + tx * 4 + b;
            if (j > i) {
                const float S = acc[a][b] * TEMP_INV;
                if (labr[a] != labc[b]) neg_local += __expf(S);
                if ((i >> 1) == (j >> 1)) pvals[i >> 1] = S;  // j == i+1, i even
            }
        }
    }

    // wave shuffle reduce -> 4 partials -> one atomic per block
    float s = neg_local;
    #pragma unroll
    for (int off = 32; off > 0; off >>= 1) s += __shfl_down(s, off, 64);
    if ((t & 63) == 0) red[t >> 6] = s;
    __syncthreads();
    if (t == 0) atomicAdd(ws, red[0] + red[1] + red[2] + red[3]);
}

__global__ void infonce_loss_kernel(const float* __restrict__ ws,
                                    float* __restrict__ out, int npairs) {
    __shared__ float red[4];
    const float neg = ws[0];
    const float* __restrict__ p = ws + 64;
    float local = 0.0f;
    for (int k = threadIdx.x; k < npairs; k += 256) {
        const float pv = p[k];
        local += logf(__expf(pv) + neg) - pv;
    }
    float s = local;
    #pragma unroll
    for (int off = 32; off > 0; off >>= 1) s += __shfl_down(s, off, 64);
    if ((threadIdx.x & 63) == 0) red[threadIdx.x >> 6] = s;
    __syncthreads();
    if (threadIdx.x == 0)
        out[0] = (red[0] + red[1] + red[2] + red[3]) / (float)npairs;
}

extern "C" void kernel_launch(void* const* d_in, const int* in_sizes, int n_in,
                              void* d_out, int out_size, void* d_ws, size_t ws_size,
                              hipStream_t stream) {
    const float* emb = (const float*)d_in[0];
    const int* labels = (const int*)d_in[1];
    float* out = (float*)d_out;
    float* ws = (float*)d_ws;

    const int ntot = in_sizes[0] / D;  // 4096
    const int npairs = ntot / 2;       // 2048 positive pairs (num_augs = 2)

    infonce_rnorm_kernel<<<ntot / 4, 256, 0, stream>>>(emb, ws, ntot);
    dim3 grid(ntot / 64, ntot / 64);
    infonce_sim_kernel<<<grid, 256, 0, stream>>>(emb, labels, ws);
    infonce_loss_kernel<<<1, 256, 0, stream>>>(ws, out, npairs);
}

// Round 2
// 129.156 us; speedup vs baseline: 2.4090x; 2.4090x over previous
//
#include <hip/hip_runtime.h>
#include <math.h>

#define D 512
#define TEMP_INV 14.285714285714286f  // 1/0.07
#define NB 32                          // 4096 / 128 block grid dim

typedef __bf16 bf16x8 __attribute__((ext_vector_type(8)));
typedef float f32x4 __attribute__((ext_vector_type(4)));

// ws layout (float units):
//   [0]              neg_sum accumulator
//   [64 .. 64+2048)  p values (positive-pair logits)
//   [4096 .. )       ebf: normalized bf16 matrix [4096][512] (4 MB), 16B aligned

// One wave per row: compute rsqrt(sum sq), scale, RNE-cast to bf16.
__global__ void infonce_norm_cast_kernel(const float* __restrict__ emb,
                                         float* __restrict__ ws, int nrows) {
    if (blockIdx.x == 0 && threadIdx.x == 0) ws[0] = 0.0f;  // zero neg_sum
    unsigned short* __restrict__ ebf = (unsigned short*)(ws + 4096);
    const int lane = threadIdx.x & 63;
    const int wave = threadIdx.x >> 6;
    const int row = blockIdx.x * 4 + wave;
    if (row >= nrows) return;
    const float* r = emb + (size_t)row * D;
    float4 v1 = *(const float4*)&r[lane * 4];
    float4 v2 = *(const float4*)&r[256 + lane * 4];
    float s = v1.x * v1.x + v1.y * v1.y + v1.z * v1.z + v1.w * v1.w
            + v2.x * v2.x + v2.y * v2.y + v2.z * v2.z + v2.w * v2.w;
    #pragma unroll
    for (int off = 32; off > 0; off >>= 1) s += __shfl_down(s, off, 64);
    const float rn = __shfl(rsqrtf(s), 0, 64);

    float f[8] = {v1.x, v1.y, v1.z, v1.w, v2.x, v2.y, v2.z, v2.w};
    unsigned short h[8];
    #pragma unroll
    for (int e = 0; e < 8; ++e) {
        unsigned int u = __float_as_uint(f[e] * rn);
        h[e] = (unsigned short)((u + 0x7FFFu + ((u >> 16) & 1u)) >> 16);  // RNE
    }
    ushort4* dst1 = (ushort4*)&ebf[(size_t)row * D + lane * 4];
    ushort4* dst2 = (ushort4*)&ebf[(size_t)row * D + 256 + lane * 4];
    *dst1 = make_ushort4(h[0], h[1], h[2], h[3]);
    *dst2 = make_ushort4(h[4], h[5], h[6], h[7]);
}

// Upper-triangular 128x128 tiles, 256 threads (4 waves), MFMA 16x16x32 bf16.
// Wave w computes the 64x64 quadrant (wy, wx) as 4x4 MFMA tiles. BK=64.
__global__ __launch_bounds__(256) void infonce_sim_kernel(
        const int* __restrict__ labels, float* __restrict__ ws) {
    // triangular decode: row-major over {(bi,bj): bj>=bi}
    int rem = blockIdx.x, bi = 0;
    while (rem >= (NB - bi)) { rem -= (NB - bi); ++bi; }
    const int bj = bi + rem;

    const unsigned short* __restrict__ ebf = (const unsigned short*)(ws + 4096);
    float* __restrict__ pvals = ws + 64;

    __shared__ unsigned short As[128 * 72];  // [row][72] bf16, +8 pad
    __shared__ unsigned short Bs[128 * 72];
    __shared__ int lab_row[128], lab_col[128];
    __shared__ float red[4];

    const int t = threadIdx.x;
    const int w = t >> 6, l = t & 63;
    const int wy = w >> 1, wx = w & 1;
    const int lq = l >> 4, lr = l & 15;  // quad, row-in-tile
    const int rowA0 = bi * 128, rowB0 = bj * 128;

    if (t < 128) lab_row[t] = labels[(rowA0 + t) >> 1];
    else lab_col[t - 128] = labels[(rowB0 + t - 128) >> 1];

    f32x4 acc[4][4] = {};

    for (int k0 = 0; k0 < D; k0 += 64) {
        uint4 ra[4], rb[4];
        #pragma unroll
        for (int s = 0; s < 4; ++s) {
            const int id = t + s * 256;        // 0..1023 chunk id
            const int row = id >> 3;           // 8 x 16B chunks per row
            const int c = id & 7;
            ra[s] = *(const uint4*)&ebf[(size_t)(rowA0 + row) * D + k0 + c * 8];
            rb[s] = *(const uint4*)&ebf[(size_t)(rowB0 + row) * D + k0 + c * 8];
        }
        __syncthreads();
        #pragma unroll
        for (int s = 0; s < 4; ++s) {
            const int id = t + s * 256;
            const int row = id >> 3;
            const int c = id & 7;
            *(uint4*)&As[row * 72 + c * 8] = ra[s];
            *(uint4*)&Bs[row * 72 + c * 8] = rb[s];
        }
        __syncthreads();
        #pragma unroll
        for (int ks = 0; ks < 2; ++ks) {
            bf16x8 af[4], bfr[4];
            #pragma unroll
            for (int mt = 0; mt < 4; ++mt)
                af[mt] = *(const bf16x8*)&As[(wy * 64 + mt * 16 + lr) * 72 + ks * 32 + lq * 8];
            #pragma unroll
            for (int nt = 0; nt < 4; ++nt)
                bfr[nt] = *(const bf16x8*)&Bs[(wx * 64 + nt * 16 + lr) * 72 + ks * 32 + lq * 8];
            #pragma unroll
            for (int mt = 0; mt < 4; ++mt)
                #pragma unroll
                for (int nt = 0; nt < 4; ++nt)
                    acc[mt][nt] = __builtin_amdgcn_mfma_f32_16x16x32_bf16(
                        af[mt], bfr[nt], acc[mt][nt], 0, 0, 0);
        }
        __syncthreads();
    }

    // Epilogue: C/D layout row=(lq*4+r), col=lr within each 16x16 tile.
    float neg_local = 0.0f;
    #pragma unroll
    for (int mt = 0; mt < 4; ++mt) {
        #pragma unroll
        for (int nt = 0; nt < 4; ++nt) {
            const f32x4 a = acc[mt][nt];
            #pragma unroll
            for (int r = 0; r < 4; ++r) {
                const int li = wy * 64 + mt * 16 + lq * 4 + r;
                const int lj = wx * 64 + nt * 16 + lr;
                const int i = rowA0 + li;
                const int j = rowB0 + lj;
                const float S = a[r] * TEMP_INV;
                if (j > i) {
                    if (lab_row[li] != lab_col[lj]) neg_local += __expf(S);
                    if (!(i & 1) && j == i + 1) pvals[i >> 1] = S;
                }
            }
        }
    }

    float s = neg_local;
    #pragma unroll
    for (int off = 32; off > 0; off >>= 1) s += __shfl_down(s, off, 64);
    if (l == 0) red[w] = s;
    __syncthreads();
    if (t == 0) atomicAdd(ws, red[0] + red[1] + red[2] + red[3]);
}

__global__ void infonce_loss_kernel(const float* __restrict__ ws,
                                    float* __restrict__ out, int npairs) {
    __shared__ float red[4];
    const float neg = ws[0];
    const float* __restrict__ p = ws + 64;
    float local = 0.0f;
    for (int k = threadIdx.x; k < npairs; k += 256) {
        const float pv = p[k];
        local += logf(__expf(pv) + neg) - pv;
    }
    float s = local;
    #pragma unroll
    for (int off = 32; off > 0; off >>= 1) s += __shfl_down(s, off, 64);
    if ((threadIdx.x & 63) == 0) red[threadIdx.x >> 6] = s;
    __syncthreads();
    if (threadIdx.x == 0)
        out[0] = (red[0] + red[1] + red[2] + red[3]) / (float)npairs;
}

extern "C" void kernel_launch(void* const* d_in, const int* in_sizes, int n_in,
                              void* d_out, int out_size, void* d_ws, size_t ws_size,
                              hipStream_t stream) {
    const float* emb = (const float*)d_in[0];
    const int* labels = (const int*)d_in[1];
    float* out = (float*)d_out;
    float* ws = (float*)d_ws;

    const int ntot = in_sizes[0] / D;  // 4096
    const int npairs = ntot / 2;       // 2048 positive pairs

    infonce_norm_cast_kernel<<<ntot / 4, 256, 0, stream>>>(emb, ws, ntot);
    const int nblk = NB * (NB + 1) / 2;  // 528 upper-tri blocks
    infonce_sim_kernel<<<nblk, 256, 0, stream>>>(labels, ws);
    infonce_loss_kernel<<<1, 256, 0, stream>>>(ws, out, npairs);
}

// Round 3
// 102.514 us; speedup vs baseline: 3.0351x; 1.2599x over previous
//
#include <hip/hip_runtime.h>
#include <math.h>

#define D 512
#define TEMP_INV 14.285714285714286f  // 1/0.07
#define NBT 64                         // 4096 / 64 tile grid dim

typedef __bf16 bf16x8 __attribute__((ext_vector_type(8)));
typedef float f32x4 __attribute__((ext_vector_type(4)));

// ws layout (float units):
//   [0]              neg_sum accumulator
//   [64 .. 64+2048)  p values (positive-pair logits)
//   [4096 .. )       ebf: normalized bf16 matrix [4096][512] (4 MB), 16B aligned

// One wave per row: compute rsqrt(sum sq), scale, RNE-cast to bf16.
__global__ void infonce_norm_cast_kernel(const float* __restrict__ emb,
                                         float* __restrict__ ws, int nrows) {
    if (blockIdx.x == 0 && threadIdx.x == 0) ws[0] = 0.0f;  // zero neg_sum
    unsigned short* __restrict__ ebf = (unsigned short*)(ws + 4096);
    const int lane = threadIdx.x & 63;
    const int wave = threadIdx.x >> 6;
    const int row = blockIdx.x * 4 + wave;
    if (row >= nrows) return;
    const float* r = emb + (size_t)row * D;
    float4 v1 = *(const float4*)&r[lane * 4];
    float4 v2 = *(const float4*)&r[256 + lane * 4];
    float s = v1.x * v1.x + v1.y * v1.y + v1.z * v1.z + v1.w * v1.w
            + v2.x * v2.x + v2.y * v2.y + v2.z * v2.z + v2.w * v2.w;
    #pragma unroll
    for (int off = 32; off > 0; off >>= 1) s += __shfl_down(s, off, 64);
    const float rn = __shfl(rsqrtf(s), 0, 64);

    float f[8] = {v1.x, v1.y, v1.z, v1.w, v2.x, v2.y, v2.z, v2.w};
    unsigned short h[8];
    #pragma unroll
    for (int e = 0; e < 8; ++e) {
        unsigned int u = __float_as_uint(f[e] * rn);
        h[e] = (unsigned short)((u + 0x7FFFu + ((u >> 16) & 1u)) >> 16);  // RNE
    }
    ushort4* dst1 = (ushort4*)&ebf[(size_t)row * D + lane * 4];
    ushort4* dst2 = (ushort4*)&ebf[(size_t)row * D + 256 + lane * 4];
    *dst1 = make_ushort4(h[0], h[1], h[2], h[3]);
    *dst2 = make_ushort4(h[4], h[5], h[6], h[7]);
}

// Upper-triangular 64x64 tiles (2080 blocks -> 4 blocks/CU), 256 threads
// (4 waves). Wave w computes rows [w*16, w*16+16) x all 64 cols as 4 MFMA
// tiles of 16x16x32 bf16. BK=64, double-buffered LDS + register prefetch:
// loads issued AFTER the barrier, consumed AFTER compute -> vmcnt wait
// overlaps compute instead of draining at the barrier. One barrier/iter.
__global__ __launch_bounds__(256, 4) void infonce_sim_kernel(
        const int* __restrict__ labels, float* __restrict__ ws) {
    // contiguous-per-XCD chunking (gridDim.x % 8 == 0 for 2080)
    const int grp = gridDim.x >> 3;
    const int tile = (blockIdx.x & 7) * grp + (blockIdx.x >> 3);
    // triangular decode: row-major over {(bi,bj): bj>=bi}
    int rem = tile, bi = 0;
    while (rem >= (NBT - bi)) { rem -= (NBT - bi); ++bi; }
    const int bj = bi + rem;

    const unsigned short* __restrict__ ebf = (const unsigned short*)(ws + 4096);
    float* __restrict__ pvals = ws + 64;

    __shared__ unsigned short As[2][64 * 72];  // [row][72] bf16, +8 pad
    __shared__ unsigned short Bs[2][64 * 72];
    __shared__ int lab_row[64], lab_col[64];
    __shared__ float red[4];

    const int t = threadIdx.x;
    const int w = t >> 6, l = t & 63;
    const int lq = l >> 4, lr = l & 15;  // quad, row-in-tile
    const int rowA0 = bi * 64, rowB0 = bj * 64;

    if (t < 64) lab_row[t] = labels[(rowA0 + t) >> 1];
    else if (t < 128) lab_col[t - 64] = labels[(rowB0 + t - 64) >> 1];

    // staging: 512 x 16B chunks per panel per K-step; thread t does chunks
    // t and t+256. row = chunk>>3 (8 chunks/row of 64 elems), c = chunk&7.
    const int srow0 = t >> 3, sc = t & 7;
    const int srow1 = srow0 + 32;
    const unsigned short* gA0 = ebf + ((size_t)(rowA0 + srow0) << 9) + sc * 8;
    const unsigned short* gA1 = ebf + ((size_t)(rowA0 + srow1) << 9) + sc * 8;
    const unsigned short* gB0 = ebf + ((size_t)(rowB0 + srow0) << 9) + sc * 8;
    const unsigned short* gB1 = ebf + ((size_t)(rowB0 + srow1) << 9) + sc * 8;
    const int lofs0 = srow0 * 72 + sc * 8;
    const int lofs1 = srow1 * 72 + sc * 8;

    f32x4 acc[4] = {};

    // prologue: K-chunk 0 into buffer 0
    {
        uint4 pa0 = *(const uint4*)gA0;
        uint4 pa1 = *(const uint4*)gA1;
        uint4 pb0 = *(const uint4*)gB0;
        uint4 pb1 = *(const uint4*)gB1;
        *(uint4*)&As[0][lofs0] = pa0;
        *(uint4*)&As[0][lofs1] = pa1;
        *(uint4*)&Bs[0][lofs0] = pb0;
        *(uint4*)&Bs[0][lofs1] = pb1;
    }

    #pragma unroll
    for (int it = 0; it < 8; ++it) {
        const int cur = it & 1;
        __syncthreads();  // publishes buffer `cur` (stored in prev iter)
        uint4 pa0, pa1, pb0, pb1;
        if (it < 7) {  // issue next K-chunk's loads; land during compute
            const int k0 = (it + 1) * 64;
            pa0 = *(const uint4*)(gA0 + k0);
            pa1 = *(const uint4*)(gA1 + k0);
            pb0 = *(const uint4*)(gB0 + k0);
            pb1 = *(const uint4*)(gB1 + k0);
        }
        #pragma unroll
        for (int ks = 0; ks < 2; ++ks) {
            const bf16x8 af = *(const bf16x8*)&As[cur][(w * 16 + lr) * 72 + ks * 32 + lq * 8];
            bf16x8 bfr[4];
            #pragma unroll
            for (int nt = 0; nt < 4; ++nt)
                bfr[nt] = *(const bf16x8*)&Bs[cur][(nt * 16 + lr) * 72 + ks * 32 + lq * 8];
            #pragma unroll
            for (int nt = 0; nt < 4; ++nt)
                acc[nt] = __builtin_amdgcn_mfma_f32_16x16x32_bf16(
                    af, bfr[nt], acc[nt], 0, 0, 0);
        }
        if (it < 7) {  // store into the other buffer; safe: one barrier/iter
            const int nxt = cur ^ 1;
            *(uint4*)&As[nxt][lofs0] = pa0;
            *(uint4*)&As[nxt][lofs1] = pa1;
            *(uint4*)&Bs[nxt][lofs0] = pb0;
            *(uint4*)&Bs[nxt][lofs1] = pb1;
        }
    }

    // Epilogue: C/D layout per 16x16 tile: row = lq*4+r, col = lr.
    float neg_local = 0.0f;
    #pragma unroll
    for (int nt = 0; nt < 4; ++nt) {
        const f32x4 a = acc[nt];
        #pragma unroll
        for (int r = 0; r < 4; ++r) {
            const int li = w * 16 + lq * 4 + r;
            const int lj = nt * 16 + lr;
            const int i = rowA0 + li;
            const int j = rowB0 + lj;
            const float S = a[r] * TEMP_INV;
            if (j > i) {
                if (lab_row[li] != lab_col[lj]) neg_local += __expf(S);
                if (!(i & 1) && j == i + 1) pvals[i >> 1] = S;
            }
        }
    }

    float s = neg_local;
    #pragma unroll
    for (int off = 32; off > 0; off >>= 1) s += __shfl_down(s, off, 64);
    if (l == 0) red[w] = s;
    __syncthreads();
    if (t == 0) atomicAdd(ws, red[0] + red[1] + red[2] + red[3]);
}

__global__ void infonce_loss_kernel(const float* __restrict__ ws,
                                    float* __restrict__ out, int npairs) {
    __shared__ float red[4];
    const float neg = ws[0];
    const float* __restrict__ p = ws + 64;
    float local = 0.0f;
    for (int k = threadIdx.x; k < npairs; k += 256) {
        const float pv = p[k];
        local += logf(__expf(pv) + neg) - pv;
    }
    float s = local;
    #pragma unroll
    for (int off = 32; off > 0; off >>= 1) s += __shfl_down(s, off, 64);
    if ((threadIdx.x & 63) == 0) red[threadIdx.x >> 6] = s;
    __syncthreads();
    if (threadIdx.x == 0)
        out[0] = (red[0] + red[1] + red[2] + red[3]) / (float)npairs;
}

extern "C" void kernel_launch(void* const* d_in, const int* in_sizes, int n_in,
                              void* d_out, int out_size, void* d_ws, size_t ws_size,
                              hipStream_t stream) {
    const float* emb = (const float*)d_in[0];
    const int* labels = (const int*)d_in[1];
    float* out = (float*)d_out;
    float* ws = (float*)d_ws;

    const int ntot = in_sizes[0] / D;  // 4096
    const int npairs = ntot / 2;       // 2048 positive pairs

    infonce_norm_cast_kernel<<<ntot / 4, 256, 0, stream>>>(emb, ws, ntot);
    const int nbt = ntot / 64;
    const int nblk = nbt * (nbt + 1) / 2;  // 2080 upper-tri tiles
    infonce_sim_kernel<<<nblk, 256, 0, stream>>>(labels, ws);
    infonce_loss_kernel<<<1, 256, 0, stream>>>(ws, out, npairs);
}